// Round 12
// baseline (316.027 us; speedup 1.0000x reference)
//
#include <hip/hip_runtime.h>
#include <hip/hip_bf16.h>
#include <math.h>

#define TLEN 8
#define BATCH 16
#define NH 16
#define HD 64
#define SLEN 4096
#define HID 1024
#define SPLITS 4
#define QSCALE 0.125f

// DPP butterfly add across 16 lanes (VALU-only, no DS ops).
#define DPP_ADD(p, ctrl)                                                     \
    do {                                                                     \
        int _t = __builtin_amdgcn_update_dpp(0, __float_as_int(p), (ctrl),   \
                                             0xF, 0xF, true);                \
        (p) += __int_as_float(_t);                                           \
    } while (0)

// ---------------------------------------------------------------------------
// proj: out[r][c] = (sum_k X[r][k] * W[c][k] + bias[c]) * scale
// ---------------------------------------------------------------------------
__global__ __launch_bounds__(256) void proj_kernel(
    const float* __restrict__ X, const float* __restrict__ W,
    const float* __restrict__ bias, float scale, float* __restrict__ out)
{
    __shared__ float xs[128][68];
    __shared__ float wt[4][68];
    const int tid = threadIdx.x;
    const int col = tid & 3;
    const int rg  = tid >> 2;
    const int c0 = blockIdx.x * 4;
    float acc0 = 0.f, acc1 = 0.f;

    for (int k0 = 0; k0 < HID; k0 += 64) {
        __syncthreads();
#pragma unroll
        for (int j = 0; j < 8; ++j) {
            int idx = tid + 256 * j;
            int r = idx >> 4, c4 = (idx & 15) * 4;
            *(float4*)&xs[r][c4] = *(const float4*)&X[(size_t)r * HID + k0 + c4];
        }
        if (tid < 64) {
            int r = tid >> 4, c4 = (tid & 15) * 4;
            *(float4*)&wt[r][c4] = *(const float4*)&W[(size_t)(c0 + r) * HID + k0 + c4];
        }
        __syncthreads();
#pragma unroll
        for (int kk = 0; kk < 64; kk += 4) {
            float4 w4 = *(const float4*)&wt[col][kk];
            float4 x0 = *(const float4*)&xs[2 * rg][kk];
            float4 x1 = *(const float4*)&xs[2 * rg + 1][kk];
            acc0 = fmaf(x0.x, w4.x, acc0); acc0 = fmaf(x0.y, w4.y, acc0);
            acc0 = fmaf(x0.z, w4.z, acc0); acc0 = fmaf(x0.w, w4.w, acc0);
            acc1 = fmaf(x1.x, w4.x, acc1); acc1 = fmaf(x1.y, w4.y, acc1);
            acc1 = fmaf(x1.z, w4.z, acc1); acc1 = fmaf(x1.w, w4.w, acc1);
        }
    }
    float bb = bias[c0 + col];
    out[(size_t)(2 * rg) * HID + c0 + col]     = (acc0 + bb) * scale;
    out[(size_t)(2 * rg + 1) * HID + c0 + col] = (acc1 + bb) * scale;
}

// ---------------------------------------------------------------------------
// compact: per batch row, gather indices of UNMASKED keys (mask==0) into
// cidx[b][0..cnt), write cnt to ccnt[b]. Also zero the 256 per-bh arrival
// counters used by the attn epilogue (re-zeroed EVERY launch -> graph-safe).
// ---------------------------------------------------------------------------
__global__ __launch_bounds__(256) void compact_kernel(
    const int* __restrict__ mask, int* __restrict__ cidx, int* __restrict__ ccnt,
    int* __restrict__ done)
{
    const int b = blockIdx.x;
    const int tid = threadIdx.x;
    __shared__ int ssum[256];
    if (tid < 16) done[b * 16 + tid] = 0;
    const int* mrow = mask + (size_t)b * SLEN;
    int loc[16];
    int cnt = 0;
#pragma unroll
    for (int j = 0; j < 16; ++j) {
        loc[j] = mrow[tid * 16 + j];
        cnt += (loc[j] == 0);
    }
    ssum[tid] = cnt;
    __syncthreads();
    for (int off = 1; off < 256; off <<= 1) {
        int v = (tid >= off) ? ssum[tid - off] : 0;
        __syncthreads();
        ssum[tid] += v;
        __syncthreads();
    }
    int pos = ssum[tid] - cnt;                 // exclusive prefix
    int* outr = cidx + (size_t)b * SLEN;
#pragma unroll
    for (int j = 0; j < 16; ++j) {
        if (loc[j] == 0) outr[pos++] = tid * 16 + j;
    }
    if (tid == 255) ccnt[b] = ssum[255];
}

// ---------------------------------------------------------------------------
// attn_partial: EXACT round-5 structure (110.3 us best known-good) plus a
// fused combine epilogue: the last-arriving of the 4 blocks per bh (device
// atomic counter + threadfence release/acquire) sums the 16 partials in
// fixed order p=0..15 (bitwise-deterministic) and writes otmp.
// ---------------------------------------------------------------------------
__global__ __launch_bounds__(256) void attn_partial_kernel(
    const float* __restrict__ Kg, const float* __restrict__ Vg,
    const int* __restrict__ cidx, const int* __restrict__ ccnt,
    const int* __restrict__ order, const float* __restrict__ qbuf,
    float* __restrict__ pacc, float* __restrict__ pl,
    int* __restrict__ done, float* __restrict__ otmp)
{
    const int split = blockIdx.x;        // 0..3
    const int bh = blockIdx.y;           // 0..255
    const int b = bh >> 4, h = bh & 15;
    const int tid = threadIdx.x;
    const int wave = tid >> 6, lane = tid & 63;
    const int g = lane >> 4;             // key-group 0..3
    const int d0 = (lane & 15) * 4;

    float4 ql[TLEN];
#pragma unroll
    for (int t = 0; t < TLEN; ++t)
        ql[t] = *(const float4*)&qbuf[(size_t)(t * BATCH + b) * HID + h * HD + d0];

    const int bsrc = order[b];
    const int cnt = ccnt[b];
    const size_t base4 = (size_t)(bsrc * NH + h) * SLEN * (HD / 4);
    const float4* kg4 = (const float4*)Kg;
    const float4* vg4 = (const float4*)Vg;

    const int p = split * 4 + wave;                      // 0..15
    const int chunk = (((cnt + 15) >> 4) + 7) & ~7;      // per-wave keys, mult of 8
    const int iters = chunk >> 3;
    const int wstart = p * chunk;
    const int* crow = cidx + (size_t)b * SLEN;

    float lsum[TLEN];
    float acc[TLEN][4];
#pragma unroll
    for (int t = 0; t < TLEN; ++t) {
        lsum[t] = 0.f;
        acc[t][0] = acc[t][1] = acc[t][2] = acc[t][3] = 0.f;
    }

// fetch compacted indices for iteration J (clamped: in-bounds garbage ok)
#define LOAD_IDX(J, IA, IB)                                                  \
    {                                                                        \
        int pa_ = wstart + (J) * 8 + g;                                      \
        int pb_ = pa_ + 4;                                                   \
        (IA) = crow[pa_ < 4095 ? pa_ : 4095];                                \
        (IB) = crow[pb_ < 4095 ? pb_ : 4095];                                \
    }

// issue K/V loads for iteration J using resident indices (invalid -> row 0)
#define LOAD_KV(J, IA, IB, KA, VA, KB, VB)                                   \
    {                                                                        \
        int pa_ = wstart + (J) * 8 + g;                                      \
        int ia_ = (pa_ < cnt) ? (IA) : 0;                                    \
        int ib_ = (pa_ + 4 < cnt) ? (IB) : 0;                                \
        size_t aa_ = base4 + (size_t)ia_ * (HD / 4) + (lane & 15);           \
        size_t ab_ = base4 + (size_t)ib_ * (HD / 4) + (lane & 15);           \
        (KA) = kg4[aa_]; (VA) = vg4[aa_];                                    \
        (KB) = kg4[ab_]; (VB) = vg4[ab_];                                    \
    }

#define BODY(IT, KA, KB, VA, VB)                                             \
    do {                                                                     \
        const int inA = (wstart + (IT) * 8 + g) >= cnt;                      \
        const int inB = (wstart + (IT) * 8 + 4 + g) >= cnt;                  \
        _Pragma("unroll")                                                    \
        for (int t = 0; t < TLEN; ++t) {                                     \
            float pa_ = ql[t].x * (KA).x + ql[t].y * (KA).y +                \
                        ql[t].z * (KA).z + ql[t].w * (KA).w;                 \
            float pb_ = ql[t].x * (KB).x + ql[t].y * (KB).y +                \
                        ql[t].z * (KB).z + ql[t].w * (KB).w;                 \
            DPP_ADD(pa_, 0xB1);  DPP_ADD(pb_, 0xB1);                         \
            DPP_ADD(pa_, 0x4E);  DPP_ADD(pb_, 0x4E);                         \
            DPP_ADD(pa_, 0x141); DPP_ADD(pb_, 0x141);                        \
            DPP_ADD(pa_, 0x140); DPP_ADD(pb_, 0x140);                        \
            float ea = inA ? 0.f : __expf(pa_);                              \
            float eb = inB ? 0.f : __expf(pb_);                              \
            lsum[t] += ea + eb;                                              \
            acc[t][0] = fmaf(ea, (VA).x, acc[t][0]);                         \
            acc[t][1] = fmaf(ea, (VA).y, acc[t][1]);                         \
            acc[t][2] = fmaf(ea, (VA).z, acc[t][2]);                         \
            acc[t][3] = fmaf(ea, (VA).w, acc[t][3]);                         \
            acc[t][0] = fmaf(eb, (VB).x, acc[t][0]);                         \
            acc[t][1] = fmaf(eb, (VB).y, acc[t][1]);                         \
            acc[t][2] = fmaf(eb, (VB).z, acc[t][2]);                         \
            acc[t][3] = fmaf(eb, (VB).w, acc[t][3]);                         \
        }                                                                    \
    } while (0)

    if (iters > 0) {
        int ia0, ib0, ia1, ib1;
        LOAD_IDX(0, ia0, ib0);
        LOAD_IDX(1, ia1, ib1);
        float4 ka, kb, va, vb;
        LOAD_KV(0, ia0, ib0, ka, va, kb, vb);

        for (int it = 0; it < iters - 1; ++it) {
            int nia, nib;
            LOAD_IDX(it + 2, nia, nib);                    // 2 ahead
            float4 nka, nkb, nva, nvb;
            LOAD_KV(it + 1, ia1, ib1, nka, nva, nkb, nvb); // 1 ahead
            BODY(it, ka, kb, va, vb);
            ka = nka; kb = nkb; va = nva; vb = nvb;
            ia1 = nia; ib1 = nib;
        }
        BODY(iters - 1, ka, kb, va, vb);
    }
#undef LOAD_IDX
#undef LOAD_KV
#undef BODY

    // merge the wave's 4 key-groups (lanes ^16, ^32 hold the same dims)
#pragma unroll
    for (int t = 0; t < TLEN; ++t) {
#pragma unroll
        for (int j = 0; j < 4; ++j) {
            acc[t][j] += __shfl_xor(acc[t][j], 16);
            acc[t][j] += __shfl_xor(acc[t][j], 32);
        }
        lsum[t] += __shfl_xor(lsum[t], 16);
        lsum[t] += __shfl_xor(lsum[t], 32);
    }

    if (lane < 16) {
        float* pa = pacc + (size_t)(bh * 16 + p) * TLEN * HD;
#pragma unroll
        for (int t = 0; t < TLEN; ++t) {
            float4 v;
            v.x = acc[t][0]; v.y = acc[t][1]; v.z = acc[t][2]; v.w = acc[t][3];
            *(float4*)&pa[t * HD + d0] = v;
        }
        if (lane == 0) {
#pragma unroll
            for (int t = 0; t < TLEN; ++t)
                pl[(size_t)(bh * 16 + p) * TLEN + t] = lsum[t];
        }
    }

    // ---- fused combine: last of the 4 blocks for this bh does it ----
    __syncthreads();            // all 4 partial writes of this block issued
    __threadfence();            // release: publish partials device-wide
    __shared__ int isLast;
    if (tid == 0) isLast = (atomicAdd(&done[bh], 1) == 3);
    __syncthreads();
    if (isLast) {
        __threadfence();        // acquire: see the other blocks' partials
        for (int i = tid; i < TLEN * HD; i += 256) {
            int t = i >> 6, d = i & 63;
            float a = 0.f, l = 0.f;
#pragma unroll
            for (int pp = 0; pp < 16; ++pp) {
                a += pacc[((size_t)(bh * 16 + pp) * TLEN + t) * HD + d];
                l += pl[(size_t)(bh * 16 + pp) * TLEN + t];
            }
            otmp[(size_t)(t * BATCH + b) * HID + h * HD + d] = a / l;
        }
    }
}

// ---------------------------------------------------------------------------
extern "C" void kernel_launch(void* const* d_in, const int* in_sizes, int n_in,
                              void* d_out, int out_size, void* d_ws, size_t ws_size,
                              hipStream_t stream) {
    const float* x     = (const float*)d_in[0];   // (8,16,1024)
    const float* pk    = (const float*)d_in[1];   // (16,16,4096,64)
    const float* pv    = (const float*)d_in[2];
    const int*   maskp = (const int*)d_in[3];     // (16,4096)
    const int*   order = (const int*)d_in[4];     // (16,)
    const float* Wq    = (const float*)d_in[5];
    const float* bq    = (const float*)d_in[6];
    const float* Wo    = (const float*)d_in[7];
    const float* bo    = (const float*)d_in[8];
    float* out = (float*)d_out;

    float* ws   = (float*)d_ws;
    float* qbuf = ws;                              // 131072 f
    float* pacc = qbuf + 128 * 1024;               // 2,097,152 f
    float* plw  = pacc + 256 * 16 * TLEN * HD;     // 32,768 f
    float* otmp = plw + 256 * 16 * TLEN;           // 131,072 f
    int*   cidx = (int*)(otmp + 128 * 1024);       // 16*4096 ints
    int*   ccnt = cidx + 16 * SLEN;                // 16 ints
    int*   done = ccnt + 16;                       // 256 ints

    compact_kernel<<<16, 256, 0, stream>>>(maskp, cidx, ccnt, done);
    proj_kernel<<<256, 256, 0, stream>>>(x, Wq, bq, QSCALE, qbuf);
    attn_partial_kernel<<<dim3(SPLITS, 256), 256, 0, stream>>>(
        pk, pv, cidx, ccnt, order, qbuf, pacc, plw, done, otmp);
    proj_kernel<<<256, 256, 0, stream>>>(otmp, Wo, bo, 1.0f, out);
}

// Round 13
// 110.454 us; speedup vs baseline: 2.8612x; 2.8612x over previous
//
#include <hip/hip_runtime.h>
#include <hip/hip_bf16.h>
#include <math.h>

#define TLEN 8
#define BATCH 16
#define NH 16
#define HD 64
#define SLEN 4096
#define HID 1024
#define SPLITS 4
#define QSCALE 0.125f

// DPP butterfly add across 16 lanes (VALU-only, no DS ops).
#define DPP_ADD(p, ctrl)                                                     \
    do {                                                                     \
        int _t = __builtin_amdgcn_update_dpp(0, __float_as_int(p), (ctrl),   \
                                             0xF, 0xF, true);                \
        (p) += __int_as_float(_t);                                           \
    } while (0)

// ---------------------------------------------------------------------------
// proj: out[r][c] = (sum_k X[r][k] * W[c][k] + bias[c]) * scale
// ---------------------------------------------------------------------------
__global__ __launch_bounds__(256) void proj_kernel(
    const float* __restrict__ X, const float* __restrict__ W,
    const float* __restrict__ bias, float scale, float* __restrict__ out)
{
    __shared__ float xs[128][68];
    __shared__ float wt[4][68];
    const int tid = threadIdx.x;
    const int col = tid & 3;
    const int rg  = tid >> 2;
    const int c0 = blockIdx.x * 4;
    float acc0 = 0.f, acc1 = 0.f;

    for (int k0 = 0; k0 < HID; k0 += 64) {
        __syncthreads();
#pragma unroll
        for (int j = 0; j < 8; ++j) {
            int idx = tid + 256 * j;
            int r = idx >> 4, c4 = (idx & 15) * 4;
            *(float4*)&xs[r][c4] = *(const float4*)&X[(size_t)r * HID + k0 + c4];
        }
        if (tid < 64) {
            int r = tid >> 4, c4 = (tid & 15) * 4;
            *(float4*)&wt[r][c4] = *(const float4*)&W[(size_t)(c0 + r) * HID + k0 + c4];
        }
        __syncthreads();
#pragma unroll
        for (int kk = 0; kk < 64; kk += 4) {
            float4 w4 = *(const float4*)&wt[col][kk];
            float4 x0 = *(const float4*)&xs[2 * rg][kk];
            float4 x1 = *(const float4*)&xs[2 * rg + 1][kk];
            acc0 = fmaf(x0.x, w4.x, acc0); acc0 = fmaf(x0.y, w4.y, acc0);
            acc0 = fmaf(x0.z, w4.z, acc0); acc0 = fmaf(x0.w, w4.w, acc0);
            acc1 = fmaf(x1.x, w4.x, acc1); acc1 = fmaf(x1.y, w4.y, acc1);
            acc1 = fmaf(x1.z, w4.z, acc1); acc1 = fmaf(x1.w, w4.w, acc1);
        }
    }
    float bb = bias[c0 + col];
    out[(size_t)(2 * rg) * HID + c0 + col]     = (acc0 + bb) * scale;
    out[(size_t)(2 * rg + 1) * HID + c0 + col] = (acc1 + bb) * scale;
}

// ---------------------------------------------------------------------------
// compact: per batch row, gather indices of UNMASKED keys (mask==0) into
// cidx[b][0..cnt), write cnt to ccnt[b]. 16 blocks x 256 threads.
// ---------------------------------------------------------------------------
__global__ __launch_bounds__(256) void compact_kernel(
    const int* __restrict__ mask, int* __restrict__ cidx, int* __restrict__ ccnt)
{
    const int b = blockIdx.x;
    const int tid = threadIdx.x;
    __shared__ int ssum[256];
    const int* mrow = mask + (size_t)b * SLEN;
    int loc[16];
    int cnt = 0;
#pragma unroll
    for (int j = 0; j < 16; ++j) {
        loc[j] = mrow[tid * 16 + j];
        cnt += (loc[j] == 0);
    }
    ssum[tid] = cnt;
    __syncthreads();
    for (int off = 1; off < 256; off <<= 1) {
        int v = (tid >= off) ? ssum[tid - off] : 0;
        __syncthreads();
        ssum[tid] += v;
        __syncthreads();
    }
    int pos = ssum[tid] - cnt;                 // exclusive prefix
    int* outr = cidx + (size_t)b * SLEN;
#pragma unroll
    for (int j = 0; j < 16; ++j) {
        if (loc[j] == 0) outr[pos++] = tid * 16 + j;
    }
    if (tid == 255) ccnt[b] = ssum[255];
}

// ---------------------------------------------------------------------------
// attn_partial: EXACT round-5 kernel (110.3 us best known-good).
// grid (SPLITS=4, 256 bh), 4 independent waves, compacted keys, 8 keys/iter,
// idx 2 iters ahead, KV 1 iter ahead, DPP dot-reduce, exp-no-max.
// ---------------------------------------------------------------------------
__global__ __launch_bounds__(256) void attn_partial_kernel(
    const float* __restrict__ Kg, const float* __restrict__ Vg,
    const int* __restrict__ cidx, const int* __restrict__ ccnt,
    const int* __restrict__ order, const float* __restrict__ qbuf,
    float* __restrict__ pacc, float* __restrict__ pl)
{
    const int split = blockIdx.x;        // 0..3
    const int bh = blockIdx.y;           // 0..255
    const int b = bh >> 4, h = bh & 15;
    const int tid = threadIdx.x;
    const int wave = tid >> 6, lane = tid & 63;
    const int g = lane >> 4;             // key-group 0..3
    const int d0 = (lane & 15) * 4;

    float4 ql[TLEN];
#pragma unroll
    for (int t = 0; t < TLEN; ++t)
        ql[t] = *(const float4*)&qbuf[(size_t)(t * BATCH + b) * HID + h * HD + d0];

    const int bsrc = order[b];
    const int cnt = ccnt[b];
    const size_t base4 = (size_t)(bsrc * NH + h) * SLEN * (HD / 4);
    const float4* kg4 = (const float4*)Kg;
    const float4* vg4 = (const float4*)Vg;

    const int p = split * 4 + wave;                      // 0..15
    const int chunk = (((cnt + 15) >> 4) + 7) & ~7;      // per-wave keys, mult of 8
    const int iters = chunk >> 3;
    const int wstart = p * chunk;
    const int* crow = cidx + (size_t)b * SLEN;

    float lsum[TLEN];
    float acc[TLEN][4];
#pragma unroll
    for (int t = 0; t < TLEN; ++t) {
        lsum[t] = 0.f;
        acc[t][0] = acc[t][1] = acc[t][2] = acc[t][3] = 0.f;
    }

// fetch compacted indices for iteration J (clamped: in-bounds garbage ok)
#define LOAD_IDX(J, IA, IB)                                                  \
    {                                                                        \
        int pa_ = wstart + (J) * 8 + g;                                      \
        int pb_ = pa_ + 4;                                                   \
        (IA) = crow[pa_ < 4095 ? pa_ : 4095];                                \
        (IB) = crow[pb_ < 4095 ? pb_ : 4095];                                \
    }

// issue K/V loads for iteration J using resident indices (invalid -> row 0)
#define LOAD_KV(J, IA, IB, KA, VA, KB, VB)                                   \
    {                                                                        \
        int pa_ = wstart + (J) * 8 + g;                                      \
        int ia_ = (pa_ < cnt) ? (IA) : 0;                                    \
        int ib_ = (pa_ + 4 < cnt) ? (IB) : 0;                                \
        size_t aa_ = base4 + (size_t)ia_ * (HD / 4) + (lane & 15);           \
        size_t ab_ = base4 + (size_t)ib_ * (HD / 4) + (lane & 15);           \
        (KA) = kg4[aa_]; (VA) = vg4[aa_];                                    \
        (KB) = kg4[ab_]; (VB) = vg4[ab_];                                    \
    }

#define BODY(IT, KA, KB, VA, VB)                                             \
    do {                                                                     \
        const int inA = (wstart + (IT) * 8 + g) >= cnt;                      \
        const int inB = (wstart + (IT) * 8 + 4 + g) >= cnt;                  \
        _Pragma("unroll")                                                    \
        for (int t = 0; t < TLEN; ++t) {                                     \
            float pa_ = ql[t].x * (KA).x + ql[t].y * (KA).y +                \
                        ql[t].z * (KA).z + ql[t].w * (KA).w;                 \
            float pb_ = ql[t].x * (KB).x + ql[t].y * (KB).y +                \
                        ql[t].z * (KB).z + ql[t].w * (KB).w;                 \
            DPP_ADD(pa_, 0xB1);  DPP_ADD(pb_, 0xB1);                         \
            DPP_ADD(pa_, 0x4E);  DPP_ADD(pb_, 0x4E);                         \
            DPP_ADD(pa_, 0x141); DPP_ADD(pb_, 0x141);                        \
            DPP_ADD(pa_, 0x140); DPP_ADD(pb_, 0x140);                        \
            float ea = inA ? 0.f : __expf(pa_);                              \
            float eb = inB ? 0.f : __expf(pb_);                              \
            lsum[t] += ea + eb;                                              \
            acc[t][0] = fmaf(ea, (VA).x, acc[t][0]);                         \
            acc[t][1] = fmaf(ea, (VA).y, acc[t][1]);                         \
            acc[t][2] = fmaf(ea, (VA).z, acc[t][2]);                         \
            acc[t][3] = fmaf(ea, (VA).w, acc[t][3]);                         \
            acc[t][0] = fmaf(eb, (VB).x, acc[t][0]);                         \
            acc[t][1] = fmaf(eb, (VB).y, acc[t][1]);                         \
            acc[t][2] = fmaf(eb, (VB).z, acc[t][2]);                         \
            acc[t][3] = fmaf(eb, (VB).w, acc[t][3]);                         \
        }                                                                    \
    } while (0)

    if (iters > 0) {
        int ia0, ib0, ia1, ib1;
        LOAD_IDX(0, ia0, ib0);
        LOAD_IDX(1, ia1, ib1);
        float4 ka, kb, va, vb;
        LOAD_KV(0, ia0, ib0, ka, va, kb, vb);

        for (int it = 0; it < iters - 1; ++it) {
            int nia, nib;
            LOAD_IDX(it + 2, nia, nib);                    // 2 ahead
            float4 nka, nkb, nva, nvb;
            LOAD_KV(it + 1, ia1, ib1, nka, nva, nkb, nvb); // 1 ahead
            BODY(it, ka, kb, va, vb);
            ka = nka; kb = nkb; va = nva; vb = nvb;
            ia1 = nia; ib1 = nib;
        }
        BODY(iters - 1, ka, kb, va, vb);
    }
#undef LOAD_IDX
#undef LOAD_KV
#undef BODY

    // merge the wave's 4 key-groups (lanes ^16, ^32 hold the same dims)
#pragma unroll
    for (int t = 0; t < TLEN; ++t) {
#pragma unroll
        for (int j = 0; j < 4; ++j) {
            acc[t][j] += __shfl_xor(acc[t][j], 16);
            acc[t][j] += __shfl_xor(acc[t][j], 32);
        }
        lsum[t] += __shfl_xor(lsum[t], 16);
        lsum[t] += __shfl_xor(lsum[t], 32);
    }

    if (lane < 16) {
        float* pa = pacc + (size_t)(bh * 16 + p) * TLEN * HD;
#pragma unroll
        for (int t = 0; t < TLEN; ++t) {
            float4 v;
            v.x = acc[t][0]; v.y = acc[t][1]; v.z = acc[t][2]; v.w = acc[t][3];
            *(float4*)&pa[t * HD + d0] = v;
        }
        if (lane == 0) {
#pragma unroll
            for (int t = 0; t < TLEN; ++t)
                pl[(size_t)(bh * 16 + p) * TLEN + t] = lsum[t];
        }
    }
}

// ---------------------------------------------------------------------------
// combine: sum 16 partials per (b,h), normalize, write (t,b,hid) layout.
// ---------------------------------------------------------------------------
__global__ __launch_bounds__(512) void combine_kernel(
    const float* __restrict__ pacc, const float* __restrict__ pl,
    float* __restrict__ otmp)
{
    const int bh = blockIdx.x, b = bh >> 4, h = bh & 15;
    const int i = threadIdx.x;           // 0..511
    const int t = i >> 6, d = i & 63;
    float a = 0.f, l = 0.f;
#pragma unroll
    for (int p = 0; p < 16; ++p) {
        a += pacc[((size_t)(bh * 16 + p) * TLEN + t) * HD + d];
        l += pl[(size_t)(bh * 16 + p) * TLEN + t];
    }
    otmp[(size_t)(t * BATCH + b) * HID + h * HD + d] = a / l;
}

// ---------------------------------------------------------------------------
extern "C" void kernel_launch(void* const* d_in, const int* in_sizes, int n_in,
                              void* d_out, int out_size, void* d_ws, size_t ws_size,
                              hipStream_t stream) {
    const float* x     = (const float*)d_in[0];   // (8,16,1024)
    const float* pk    = (const float*)d_in[1];   // (16,16,4096,64)
    const float* pv    = (const float*)d_in[2];
    const int*   maskp = (const int*)d_in[3];     // (16,4096)
    const int*   order = (const int*)d_in[4];     // (16,)
    const float* Wq    = (const float*)d_in[5];
    const float* bq    = (const float*)d_in[6];
    const float* Wo    = (const float*)d_in[7];
    const float* bo    = (const float*)d_in[8];
    float* out = (float*)d_out;

    float* ws   = (float*)d_ws;
    float* qbuf = ws;                              // 131072 f
    float* pacc = qbuf + 128 * 1024;               // 2,097,152 f
    float* plw  = pacc + 256 * 16 * TLEN * HD;     // 32,768 f
    float* otmp = plw + 256 * 16 * TLEN;           // 131,072 f
    int*   cidx = (int*)(otmp + 128 * 1024);       // 16*4096 ints
    int*   ccnt = cidx + 16 * SLEN;                // 16 ints

    compact_kernel<<<16, 256, 0, stream>>>(maskp, cidx, ccnt);
    proj_kernel<<<256, 256, 0, stream>>>(x, Wq, bq, QSCALE, qbuf);
    attn_partial_kernel<<<dim3(SPLITS, 256), 256, 0, stream>>>(
        pk, pv, cidx, ccnt, order, qbuf, pacc, plw);
    combine_kernel<<<256, 512, 0, stream>>>(pacc, plw, otmp);
    proj_kernel<<<256, 256, 0, stream>>>(otmp, Wo, bo, 1.0f, out);
}